// Round 4
// baseline (44.017 us; speedup 1.0000x reference)
//
#include <hip/hip_runtime.h>
#include <math.h>

#define HH 128
#define WW 128
#define TT 8
#define NG 1024
#define PP (HH * WW * TT)      // 131072 pixels
#define P3 (PP * 3)            // 393216 floats per full image

// ---------------------------------------------------------------------------
// Kernel 1: per-(pixel-block, gaussian-chunk) partial blend.
// Block = 256 threads = 4 rows (r = t*128 + y); each wave owns one row;
// each thread owns pixels x and x+64 of its row, in plain scalar fp32
// (packed fp32 is NOT double-rate on MI355X, and vector builds cost movs).
// blockIdx.y selects a CHUNK-sized slice of the gaussians.
// FINAL=true  -> single chunk, clip and write directly to out.
// FINAL=false -> write unclipped partial to dst + blockIdx.y * P3.
// LDS per gaussian: {A, f0*op, f1*op, f2*op, B0,C0, B1,C1, B2,C2, B3,C3}.
// ---------------------------------------------------------------------------
template <int CHUNK, bool FINAL>
__global__ __launch_bounds__(256) void gv_partial(
    const float* __restrict__ xyz,
    const float* __restrict__ chol,
    const float* __restrict__ feat,
    const float* __restrict__ opac,
    float* __restrict__ dst)
{
    __shared__ __align__(16) float lds[CHUNK * 12];

    const int tid = threadIdx.x;
    const int r0 = blockIdx.x * 4;          // first row index (r = t*128 + y)
    const int g0 = blockIdx.y * CHUNK;      // first gaussian of this chunk

    const float kneg = -1.44269504088896340736f;  // -log2(e)

    // ---- per-gaussian setup ----
    for (int k = tid; k < CHUNK; k += 256) {
        const int n = g0 + k;
        float vx = xyz[n * 3 + 0], vy = xyz[n * 3 + 1], vt = xyz[n * 3 + 2];
        float mx = 0.5f * ((tanhf(vx) + 1.f) * (float)WW - 1.f);
        float my = 0.5f * ((tanhf(vy) + 1.f) * (float)HH - 1.f);
        float mt = 0.5f * ((tanhf(vt) + 1.f) * (float)TT - 1.f);

        float c0 = chol[n * 6 + 0] + 0.5f;
        float c1 = chol[n * 6 + 1];
        float c2 = chol[n * 6 + 2] + 0.5f;
        float c3 = chol[n * 6 + 3] + 0.5f;
        float c4 = chol[n * 6 + 4];
        float c5 = chol[n * 6 + 5] + 0.5f;

        // Sigma = L L^T, L = [[c0,0,0],[c1,c3,0],[c2,c4,c5]]
        float a  = c0 * c0;
        float b  = c0 * c1;
        float cc = c0 * c2;
        float d  = c1 * c1 + c3 * c3;
        float e  = c1 * c2 + c3 * c4;
        float f  = c2 * c2 + c4 * c4 + c5 * c5;

        // symmetric 3x3 inverse via adjugate
        float A00 = d * f - e * e;
        float A01 = cc * e - b * f;
        float A02 = b * e - cc * d;
        float A11 = a * f - cc * cc;
        float A12 = b * cc - a * e;
        float A22 = a * d - b * b;
        float det = a * A00 + b * A01 + cc * A02;
        float rdet = 1.f / det;
        float Q00 = A00 * rdet, Q01 = A01 * rdet, Q02 = A02 * rdet;
        float Q11 = A11 * rdet, Q12 = A12 * rdet, Q22 = A22 * rdet;

        float qmx = Q00 * mx + Q01 * my + Q02 * mt;
        float qmy = Q01 * mx + Q11 * my + Q12 * mt;
        float qmt = Q02 * mx + Q12 * my + Q22 * mt;
        float cst = 0.5f * (mx * qmx + my * qmy + mt * qmt);

        float G0 = 0.5f * Q00, G1 = 0.5f * Q11, G2 = 0.5f * Q22;
        float G3 = Q01, G4 = Q02, G5 = Q12;
        float G6 = -qmx, G7 = -qmy, G8 = -qmt, G9 = cst;

        float A_ = kneg * G0;
        float op = opac[n];
        lds[k * 12 + 0] = A_;
        lds[k * 12 + 1] = op * feat[n * 3 + 0];
        lds[k * 12 + 2] = op * feat[n * 3 + 1];
        lds[k * 12 + 3] = op * feat[n * 3 + 2];
#pragma unroll
        for (int rr = 0; rr < 4; ++rr) {
            const int r = r0 + rr;
            const float yf = (float)(r & 127);
            const float tf = (float)(r >> 7);
            float B_ = kneg * (G3 * yf + G4 * tf + G6);
            float C_ = kneg * (G1 * yf * yf + G2 * tf * tf + G5 * yf * tf
                               + G7 * yf + G8 * tf + G9);
            lds[k * 12 + 4 + 2 * rr] = B_;
            lds[k * 12 + 5 + 2 * rr] = C_;
        }
    }
    __syncthreads();

    // ---- inner loop: CHUNK gaussians, 2 pixels per thread, scalar fp32 ----
    const int wv = tid >> 6;                 // wave index = row within block
    const float x1 = (float)(tid & 63);
    const float x2 = x1 + 64.f;
    float a0 = 0.f, a1 = 0.f, a2 = 0.f;      // pixel 1 channels
    float b0 = 0.f, b1 = 0.f, b2 = 0.f;      // pixel 2 channels
    const float4* lds4 = (const float4*)lds;

#pragma unroll 8
    for (int k = 0; k < CHUNK; ++k) {
        float4 af = lds4[k * 3];                             // {A, fc0, fc1, fc2}
        float2 bc = *(const float2*)&lds[k * 12 + 4 + 2 * wv]; // {B, C} my row
        float s1 = fmaf(fmaf(af.x, x1, bc.x), x1, bc.y);     // -log2e * sigma
        float s2 = fmaf(fmaf(af.x, x2, bc.x), x2, bc.y);
        float w1 = __builtin_amdgcn_exp2f(s1);
        float w2 = __builtin_amdgcn_exp2f(s2);
        a0 = fmaf(w1, af.y, a0);
        a1 = fmaf(w1, af.z, a1);
        a2 = fmaf(w1, af.w, a2);
        b0 = fmaf(w2, af.y, b0);
        b1 = fmaf(w2, af.z, b1);
        b2 = fmaf(w2, af.w, b2);
    }

    if (FINAL) {
        a0 = fminf(fmaxf(a0, 0.f), 1.f);
        a1 = fminf(fmaxf(a1, 0.f), 1.f);
        a2 = fminf(fmaxf(a2, 0.f), 1.f);
        b0 = fminf(fmaxf(b0, 0.f), 1.f);
        b1 = fminf(fmaxf(b1, 0.f), 1.f);
        b2 = fminf(fmaxf(b2, 0.f), 1.f);
    }

    // layout: [3][H][W][T], base = (y*W + x)*T + t ; second pixel at x+64
    const int r = r0 + wv;
    const int y = r & 127, t = r >> 7;
    const int x = tid & 63;
    const int base = (y * WW + x) * TT + t;
    float* d = FINAL ? dst : (dst + (size_t)blockIdx.y * P3);
    d[base] = a0;
    d[base + 64 * TT] = b0;
    d[base + PP] = a1;
    d[base + PP + 64 * TT] = b1;
    d[base + 2 * PP] = a2;
    d[base + 2 * PP + 64 * TT] = b2;
}

// ---------------------------------------------------------------------------
// Kernel 2: sum SPLIT partials, clip, write out. Pure memory-bound.
// ---------------------------------------------------------------------------
__global__ __launch_bounds__(256) void gv_reduce(
    const float* __restrict__ ws, float* __restrict__ out, int split)
{
    const int i = blockIdx.x * 256 + threadIdx.x;   // float4 index, P3/4 total
    const float4* w4 = (const float4*)ws;
    float4 a = w4[i];
    for (int s = 1; s < split; ++s) {
        float4 b = w4[(size_t)s * (P3 / 4) + i];
        a.x += b.x; a.y += b.y; a.z += b.z; a.w += b.w;
    }
    a.x = fminf(fmaxf(a.x, 0.f), 1.f);
    a.y = fminf(fmaxf(a.y, 0.f), 1.f);
    a.z = fminf(fmaxf(a.z, 0.f), 1.f);
    a.w = fminf(fmaxf(a.w, 0.f), 1.f);
    ((float4*)out)[i] = a;
}

extern "C" void kernel_launch(void* const* d_in, const int* in_sizes, int n_in,
                              void* d_out, int out_size, void* d_ws, size_t ws_size,
                              hipStream_t stream) {
    const float* xyz  = (const float*)d_in[0];
    const float* chol = (const float*)d_in[1];
    const float* feat = (const float*)d_in[2];
    const float* opac = (const float*)d_in[3];
    float* out = (float*)d_out;
    float* ws  = (float*)d_ws;

    const int pixel_blocks = (PP / 128) / 4;         // 256 blocks, 4 rows each
    const size_t bytes_per_split = (size_t)P3 * sizeof(float);

    if (ws_size >= 8 * bytes_per_split) {
        gv_partial<128, false><<<dim3(pixel_blocks, 8), 256, 0, stream>>>(
            xyz, chol, feat, opac, ws);
        gv_reduce<<<P3 / 4 / 256, 256, 0, stream>>>(ws, out, 8);
    } else if (ws_size >= 4 * bytes_per_split) {
        gv_partial<256, false><<<dim3(pixel_blocks, 4), 256, 0, stream>>>(
            xyz, chol, feat, opac, ws);
        gv_reduce<<<P3 / 4 / 256, 256, 0, stream>>>(ws, out, 4);
    } else if (ws_size >= 2 * bytes_per_split) {
        gv_partial<512, false><<<dim3(pixel_blocks, 2), 256, 0, stream>>>(
            xyz, chol, feat, opac, ws);
        gv_reduce<<<P3 / 4 / 256, 256, 0, stream>>>(ws, out, 2);
    } else {
        gv_partial<1024, true><<<dim3(pixel_blocks, 1), 256, 0, stream>>>(
            xyz, chol, feat, opac, out);
    }
}

// Round 5
// 25.982 us; speedup vs baseline: 1.6942x; 1.6942x over previous
//
#include <hip/hip_runtime.h>
#include <math.h>

#define HH 128
#define WW 128
#define TT 8
#define NG 1024
#define PP (HH * WW * TT)      // 131072 pixels
#define P3 (PP * 3)            // 393216 floats per full image

// ---------------------------------------------------------------------------
// Culled partial-blend kernel.
// Block = 256 threads = 4 waves; wave w owns row r0+w (r = t*128 + y, one t
// per block since 128 % 4 == 0); each lane owns pixels x and x+64.
// blockIdx.y selects a CHUNK-sized gaussian slice.
// Phase 1 (tid < CHUNK): compute G for gaussian g0+tid from raw inputs,
//   per-row quadratic-in-x coeffs B,C (natural units), visibility test
//   min_x sigma = C - B^2/(4 G0) < 16 over the block's 4 rows.
// Phase 2: deterministic ballot compaction -> LDS records (kneg-scaled)
//   {A, f0*op, f1*op, f2*op, B0,C0, B1,C1, B2,C2, B3,C3}.
// Phase 3: all 4 waves loop over S survivors: Horner + exp2 + blend.
// Unclipped partial written to dst + blockIdx.y * P3.
// ---------------------------------------------------------------------------
template <int CHUNK>
__global__ __launch_bounds__(256) void gv_cull(
    const float* __restrict__ xyz,
    const float* __restrict__ chol,
    const float* __restrict__ feat,
    const float* __restrict__ opac,
    float* __restrict__ dst)
{
    static_assert(CHUNK == 128 || CHUNK == 256, "chunk");
    __shared__ __align__(16) float recs[CHUNK * 12];
    __shared__ int cnt_lds[4];

    const int tid = threadIdx.x;
    const int lane = tid & 63;
    const int wv = tid >> 6;                // wave index = row within block
    const int r0 = blockIdx.x * 4;          // first row (same t for all 4)
    const int g0 = blockIdx.y * CHUNK;

    const float kneg = -1.44269504088896340736f;  // -log2(e)
    const float y0f = (float)(r0 & 127);
    const float tf = (float)(r0 >> 7);

    // ---- phase 1: G + per-row coeffs + visibility test ----
    bool keep = false;
    float A_ = 0.f, fc0 = 0.f, fc1 = 0.f, fc2 = 0.f;
    float Brow[4], Crow[4];

    if (tid < CHUNK) {
        const int n = g0 + tid;
        float vx = xyz[n * 3 + 0], vy = xyz[n * 3 + 1], vt = xyz[n * 3 + 2];
        float mx = 0.5f * ((tanhf(vx) + 1.f) * (float)WW - 1.f);
        float my = 0.5f * ((tanhf(vy) + 1.f) * (float)HH - 1.f);
        float mt = 0.5f * ((tanhf(vt) + 1.f) * (float)TT - 1.f);

        float c0 = chol[n * 6 + 0] + 0.5f;
        float c1 = chol[n * 6 + 1];
        float c2 = chol[n * 6 + 2] + 0.5f;
        float c3 = chol[n * 6 + 3] + 0.5f;
        float c4 = chol[n * 6 + 4];
        float c5 = chol[n * 6 + 5] + 0.5f;

        // Sigma = L L^T
        float a  = c0 * c0;
        float b  = c0 * c1;
        float cc = c0 * c2;
        float d  = c1 * c1 + c3 * c3;
        float e  = c1 * c2 + c3 * c4;
        float f  = c2 * c2 + c4 * c4 + c5 * c5;

        // symmetric 3x3 inverse via adjugate
        float A00 = d * f - e * e;
        float A01 = cc * e - b * f;
        float A02 = b * e - cc * d;
        float A11 = a * f - cc * cc;
        float A12 = b * cc - a * e;
        float A22 = a * d - b * b;
        float det = a * A00 + b * A01 + cc * A02;
        float rdet = 1.f / det;
        float Q00 = A00 * rdet, Q01 = A01 * rdet, Q02 = A02 * rdet;
        float Q11 = A11 * rdet, Q12 = A12 * rdet, Q22 = A22 * rdet;

        float qmx = Q00 * mx + Q01 * my + Q02 * mt;
        float qmy = Q01 * mx + Q11 * my + Q12 * mt;
        float qmt = Q02 * mx + Q12 * my + Q22 * mt;
        float cst = 0.5f * (mx * qmx + my * qmy + mt * qmt);

        float G0 = 0.5f * Q00, G1 = 0.5f * Q11, G2 = 0.5f * Q22;
        float G3 = Q01, G4 = Q02, G5 = Q12;
        float G6 = -qmx, G7 = -qmy, G8 = -qmt, G9 = cst;

        // shared-in-t pieces
        float u  = fmaf(G4, tf, G6);                      // x-linear const
        float v  = fmaf(G5, tf, G7);                      // y-linear const
        float w0 = fmaf(fmaf(G2, tf, G8), tf, G9);        // const
        float inv4 = 0.25f / G0;                          // >0 (PD)

        float smin = 1e30f;
#pragma unroll
        for (int rr = 0; rr < 4; ++rr) {
            float yf = y0f + (float)rr;
            float B = fmaf(G3, yf, u);
            float C = fmaf(fmaf(G1, yf, v), yf, w0);
            Brow[rr] = B;
            Crow[rr] = C;
            smin = fminf(smin, fmaf(-B * B, inv4, C));    // unclamped min_x
        }
        keep = smin < 16.0f;                              // e^-16 ~ 1.1e-7

        float op = opac[n];
        A_  = kneg * G0;
        fc0 = op * feat[n * 3 + 0];
        fc1 = op * feat[n * 3 + 1];
        fc2 = op * feat[n * 3 + 2];
    }

    // ---- phase 2: deterministic compaction (index-ordered) ----
    unsigned long long mask = __ballot(keep);
    if (lane == 0) cnt_lds[wv] = (int)__popcll(mask);
    if (wv >= CHUNK / 64 && lane == 0) cnt_lds[wv] = 0;   // non-cull waves
    __syncthreads();

    int base = 0;
    for (int w = 0; w < wv; ++w) base += cnt_lds[w];
    int S = cnt_lds[0] + cnt_lds[1] + cnt_lds[2] + cnt_lds[3];
    S = __builtin_amdgcn_readfirstlane(S);

    if (keep) {
        int pos = __builtin_amdgcn_mbcnt_hi(
                      (unsigned)(mask >> 32),
                      __builtin_amdgcn_mbcnt_lo((unsigned)mask, 0));
        int slot = base + pos;
        float4* r4 = (float4*)recs;
        r4[slot * 3 + 0] = (float4){A_, fc0, fc1, fc2};
        r4[slot * 3 + 1] = (float4){kneg * Brow[0], kneg * Crow[0],
                                    kneg * Brow[1], kneg * Crow[1]};
        r4[slot * 3 + 2] = (float4){kneg * Brow[2], kneg * Crow[2],
                                    kneg * Brow[3], kneg * Crow[3]};
    }
    __syncthreads();

    // ---- phase 3: blend S survivors, 2 px per thread ----
    const float x1 = (float)lane;
    const float x2 = x1 + 64.f;
    float a0 = 0.f, a1 = 0.f, a2 = 0.f;
    float b0 = 0.f, b1 = 0.f, b2 = 0.f;
    const float4* lds4 = (const float4*)recs;

#pragma unroll 2
    for (int m = 0; m < S; ++m) {
        float4 af = lds4[m * 3];                               // {A,f0,f1,f2}
        float2 bc = *(const float2*)&recs[m * 12 + 4 + 2 * wv]; // {B,C} my row
        float s1 = fmaf(fmaf(af.x, x1, bc.x), x1, bc.y);
        float s2 = fmaf(fmaf(af.x, x2, bc.x), x2, bc.y);
        float w1 = __builtin_amdgcn_exp2f(s1);
        float w2 = __builtin_amdgcn_exp2f(s2);
        a0 = fmaf(w1, af.y, a0);
        a1 = fmaf(w1, af.z, a1);
        a2 = fmaf(w1, af.w, a2);
        b0 = fmaf(w2, af.y, b0);
        b1 = fmaf(w2, af.z, b1);
        b2 = fmaf(w2, af.w, b2);
    }

    // layout: [3][H][W][T], base = (y*W + x)*T + t ; second pixel at x+64
    const int r = r0 + wv;
    const int y = r & 127, t = r >> 7;
    const int base_o = (y * WW + lane) * TT + t;
    float* d = dst + (size_t)blockIdx.y * P3;
    d[base_o] = a0;
    d[base_o + 64 * TT] = b0;
    d[base_o + PP] = a1;
    d[base_o + PP + 64 * TT] = b1;
    d[base_o + 2 * PP] = a2;
    d[base_o + 2 * PP + 64 * TT] = b2;
}

// ---------------------------------------------------------------------------
// Dense fallback (no workspace): R4's kernel, clip + write out directly.
// ---------------------------------------------------------------------------
__global__ __launch_bounds__(256) void gv_dense(
    const float* __restrict__ xyz,
    const float* __restrict__ chol,
    const float* __restrict__ feat,
    const float* __restrict__ opac,
    float* __restrict__ dst)
{
    __shared__ __align__(16) float lds[1024 * 12];

    const int tid = threadIdx.x;
    const int r0 = blockIdx.x * 4;
    const float kneg = -1.44269504088896340736f;

    for (int k = tid; k < 1024; k += 256) {
        const int n = k;
        float vx = xyz[n * 3 + 0], vy = xyz[n * 3 + 1], vt = xyz[n * 3 + 2];
        float mx = 0.5f * ((tanhf(vx) + 1.f) * (float)WW - 1.f);
        float my = 0.5f * ((tanhf(vy) + 1.f) * (float)HH - 1.f);
        float mt = 0.5f * ((tanhf(vt) + 1.f) * (float)TT - 1.f);
        float c0 = chol[n * 6 + 0] + 0.5f;
        float c1 = chol[n * 6 + 1];
        float c2 = chol[n * 6 + 2] + 0.5f;
        float c3 = chol[n * 6 + 3] + 0.5f;
        float c4 = chol[n * 6 + 4];
        float c5 = chol[n * 6 + 5] + 0.5f;
        float a  = c0 * c0, b = c0 * c1, cc = c0 * c2;
        float d  = c1 * c1 + c3 * c3;
        float e  = c1 * c2 + c3 * c4;
        float f  = c2 * c2 + c4 * c4 + c5 * c5;
        float A00 = d * f - e * e, A01 = cc * e - b * f, A02 = b * e - cc * d;
        float A11 = a * f - cc * cc, A12 = b * cc - a * e, A22 = a * d - b * b;
        float det = a * A00 + b * A01 + cc * A02;
        float rdet = 1.f / det;
        float Q00 = A00 * rdet, Q01 = A01 * rdet, Q02 = A02 * rdet;
        float Q11 = A11 * rdet, Q12 = A12 * rdet, Q22 = A22 * rdet;
        float qmx = Q00 * mx + Q01 * my + Q02 * mt;
        float qmy = Q01 * mx + Q11 * my + Q12 * mt;
        float qmt = Q02 * mx + Q12 * my + Q22 * mt;
        float cst = 0.5f * (mx * qmx + my * qmy + mt * qmt);
        float G0 = 0.5f * Q00, G1 = 0.5f * Q11, G2 = 0.5f * Q22;
        float G3 = Q01, G4 = Q02, G5 = Q12;
        float G6 = -qmx, G7 = -qmy, G8 = -qmt, G9 = cst;
        float op = opac[n];
        lds[k * 12 + 0] = kneg * G0;
        lds[k * 12 + 1] = op * feat[n * 3 + 0];
        lds[k * 12 + 2] = op * feat[n * 3 + 1];
        lds[k * 12 + 3] = op * feat[n * 3 + 2];
#pragma unroll
        for (int rr = 0; rr < 4; ++rr) {
            const int r = r0 + rr;
            const float yf = (float)(r & 127);
            const float tf = (float)(r >> 7);
            lds[k * 12 + 4 + 2 * rr] = kneg * (G3 * yf + G4 * tf + G6);
            lds[k * 12 + 5 + 2 * rr] = kneg * (G1 * yf * yf + G2 * tf * tf
                + G5 * yf * tf + G7 * yf + G8 * tf + G9);
        }
    }
    __syncthreads();

    const int wv = tid >> 6;
    const float x1 = (float)(tid & 63);
    const float x2 = x1 + 64.f;
    float a0 = 0.f, a1 = 0.f, a2 = 0.f;
    float b0 = 0.f, b1 = 0.f, b2 = 0.f;
    const float4* lds4 = (const float4*)lds;

#pragma unroll 8
    for (int k = 0; k < 1024; ++k) {
        float4 af = lds4[k * 3];
        float2 bc = *(const float2*)&lds[k * 12 + 4 + 2 * wv];
        float s1 = fmaf(fmaf(af.x, x1, bc.x), x1, bc.y);
        float s2 = fmaf(fmaf(af.x, x2, bc.x), x2, bc.y);
        float w1 = __builtin_amdgcn_exp2f(s1);
        float w2 = __builtin_amdgcn_exp2f(s2);
        a0 = fmaf(w1, af.y, a0); a1 = fmaf(w1, af.z, a1); a2 = fmaf(w1, af.w, a2);
        b0 = fmaf(w2, af.y, b0); b1 = fmaf(w2, af.z, b1); b2 = fmaf(w2, af.w, b2);
    }

    a0 = fminf(fmaxf(a0, 0.f), 1.f); a1 = fminf(fmaxf(a1, 0.f), 1.f);
    a2 = fminf(fmaxf(a2, 0.f), 1.f); b0 = fminf(fmaxf(b0, 0.f), 1.f);
    b1 = fminf(fmaxf(b1, 0.f), 1.f); b2 = fminf(fmaxf(b2, 0.f), 1.f);

    const int r = r0 + wv;
    const int y = r & 127, t = r >> 7;
    const int base = (y * WW + (tid & 63)) * TT + t;
    dst[base] = a0;
    dst[base + 64 * TT] = b0;
    dst[base + PP] = a1;
    dst[base + PP + 64 * TT] = b1;
    dst[base + 2 * PP] = a2;
    dst[base + 2 * PP + 64 * TT] = b2;
}

// ---------------------------------------------------------------------------
// Reduce: sum SPLIT partials, clip, write out.
// ---------------------------------------------------------------------------
__global__ __launch_bounds__(256) void gv_reduce(
    const float* __restrict__ ws, float* __restrict__ out, int split)
{
    const int i = blockIdx.x * 256 + threadIdx.x;
    const float4* w4 = (const float4*)ws;
    float4 a = w4[i];
    for (int s = 1; s < split; ++s) {
        float4 b = w4[(size_t)s * (P3 / 4) + i];
        a.x += b.x; a.y += b.y; a.z += b.z; a.w += b.w;
    }
    a.x = fminf(fmaxf(a.x, 0.f), 1.f);
    a.y = fminf(fmaxf(a.y, 0.f), 1.f);
    a.z = fminf(fmaxf(a.z, 0.f), 1.f);
    a.w = fminf(fmaxf(a.w, 0.f), 1.f);
    ((float4*)out)[i] = a;
}

extern "C" void kernel_launch(void* const* d_in, const int* in_sizes, int n_in,
                              void* d_out, int out_size, void* d_ws, size_t ws_size,
                              hipStream_t stream) {
    const float* xyz  = (const float*)d_in[0];
    const float* chol = (const float*)d_in[1];
    const float* feat = (const float*)d_in[2];
    const float* opac = (const float*)d_in[3];
    float* out = (float*)d_out;
    float* ws  = (float*)d_ws;

    const int pixel_blocks = (TT * HH) / 4;          // 256 blocks of 4 rows
    const size_t bytes_per_split = (size_t)P3 * sizeof(float);

    if (ws_size >= 8 * bytes_per_split) {
        gv_cull<128><<<dim3(pixel_blocks, 8), 256, 0, stream>>>(
            xyz, chol, feat, opac, ws);
        gv_reduce<<<P3 / 4 / 256, 256, 0, stream>>>(ws, out, 8);
    } else if (ws_size >= 4 * bytes_per_split) {
        gv_cull<256><<<dim3(pixel_blocks, 4), 256, 0, stream>>>(
            xyz, chol, feat, opac, ws);
        gv_reduce<<<P3 / 4 / 256, 256, 0, stream>>>(ws, out, 4);
    } else {
        gv_dense<<<pixel_blocks, 256, 0, stream>>>(
            xyz, chol, feat, opac, out);
    }
}

// Round 6
// 21.695 us; speedup vs baseline: 2.0289x; 1.1976x over previous
//
#include <hip/hip_runtime.h>
#include <math.h>

#define HH 128
#define WW 128
#define TT 8
#define NG 1024
#define PP (HH * WW * TT)      // 131072 pixels
#define P3 (PP * 3)            // 393216 floats per full image
#define RECF 16                // floats per precomputed gaussian record
#define RECTOT (NG * RECF)     // 16384 floats
#define SPLIT 4
#define CHUNK 256              // NG / SPLIT

// ---------------------------------------------------------------------------
// Kernel A: per-gaussian setup, once. Record (float4 x4):
//   {G0,G1,G2,G3} {G4,G5,G6,G7} {G8,G9,inv4,0} {fc0,fc1,fc2,0}
// sigma(p) = G0 x^2 + G1 y^2 + G2 t^2 + G3 xy + G4 xt + G5 yt
//          + G6 x + G7 y + G8 t + G9 ;  inv4 = 0.25/G0
// ---------------------------------------------------------------------------
__global__ __launch_bounds__(256) void gv_prep(
    const float* __restrict__ xyz,
    const float* __restrict__ chol,
    const float* __restrict__ feat,
    const float* __restrict__ opac,
    float* __restrict__ recs_g)
{
    const int n = blockIdx.x * 256 + threadIdx.x;
    if (n >= NG) return;

    float vx = xyz[n * 3 + 0], vy = xyz[n * 3 + 1], vt = xyz[n * 3 + 2];
    float mx = 0.5f * ((tanhf(vx) + 1.f) * (float)WW - 1.f);
    float my = 0.5f * ((tanhf(vy) + 1.f) * (float)HH - 1.f);
    float mt = 0.5f * ((tanhf(vt) + 1.f) * (float)TT - 1.f);

    float c0 = chol[n * 6 + 0] + 0.5f;
    float c1 = chol[n * 6 + 1];
    float c2 = chol[n * 6 + 2] + 0.5f;
    float c3 = chol[n * 6 + 3] + 0.5f;
    float c4 = chol[n * 6 + 4];
    float c5 = chol[n * 6 + 5] + 0.5f;

    // Sigma = L L^T
    float a  = c0 * c0;
    float b  = c0 * c1;
    float cc = c0 * c2;
    float d  = c1 * c1 + c3 * c3;
    float e  = c1 * c2 + c3 * c4;
    float f  = c2 * c2 + c4 * c4 + c5 * c5;

    // symmetric 3x3 inverse via adjugate
    float A00 = d * f - e * e;
    float A01 = cc * e - b * f;
    float A02 = b * e - cc * d;
    float A11 = a * f - cc * cc;
    float A12 = b * cc - a * e;
    float A22 = a * d - b * b;
    float det = a * A00 + b * A01 + cc * A02;
    float rdet = 1.f / det;
    float Q00 = A00 * rdet, Q01 = A01 * rdet, Q02 = A02 * rdet;
    float Q11 = A11 * rdet, Q12 = A12 * rdet, Q22 = A22 * rdet;

    float qmx = Q00 * mx + Q01 * my + Q02 * mt;
    float qmy = Q01 * mx + Q11 * my + Q12 * mt;
    float qmt = Q02 * mx + Q12 * my + Q22 * mt;
    float cst = 0.5f * (mx * qmx + my * qmy + mt * qmt);

    float G0 = 0.5f * Q00, G1 = 0.5f * Q11, G2 = 0.5f * Q22;
    float G3 = Q01, G4 = Q02, G5 = Q12;
    float G6 = -qmx, G7 = -qmy, G8 = -qmt, G9 = cst;

    float op = opac[n];
    float4* r4 = (float4*)recs_g;
    r4[n * 4 + 0] = (float4){G0, G1, G2, G3};
    r4[n * 4 + 1] = (float4){G4, G5, G6, G7};
    r4[n * 4 + 2] = (float4){G8, G9, 0.25f / G0, 0.f};
    r4[n * 4 + 3] = (float4){op * feat[n * 3 + 0], op * feat[n * 3 + 1],
                             op * feat[n * 3 + 2], 0.f};
}

// ---------------------------------------------------------------------------
// Kernel B: culled partial blend.
// Block = 256 threads = 4 waves; wave w owns row r0+w (t constant per block);
// each lane owns pixels x and x+64. blockIdx.y = gaussian chunk.
// Phase 1: load record for gaussian g0+tid, fold t, per-row B,C, vertex-min
//   visibility test (min_x sigma < 16).
// Phase 2: deterministic index-ordered ballot compaction into LDS.
// Phase 3: blend S survivors. Unclipped partial -> dst + blockIdx.y*P3.
// ---------------------------------------------------------------------------
__global__ __launch_bounds__(256) void gv_cull(
    const float* __restrict__ recs_g,
    float* __restrict__ dst)
{
    __shared__ __align__(16) float recs[CHUNK * 12];
    __shared__ int cnt_lds[4];

    const int tid = threadIdx.x;
    const int lane = tid & 63;
    const int wv = tid >> 6;
    const int r0 = blockIdx.x * 4;          // 4 rows, same t
    const int g0 = blockIdx.y * CHUNK;

    const float kneg = -1.44269504088896340736f;  // -log2(e)
    const float y0f = (float)(r0 & 127);
    const float tf = (float)(r0 >> 7);

    // ---- phase 1: load record, fold t, row coeffs + visibility ----
    const float4* g4 = (const float4*)recs_g;
    const int n = g0 + tid;
    float4 ra = g4[n * 4 + 0];   // G0 G1 G2 G3
    float4 rb = g4[n * 4 + 1];   // G4 G5 G6 G7
    float4 rc = g4[n * 4 + 2];   // G8 G9 inv4 -
    float4 rd = g4[n * 4 + 3];   // fc0 fc1 fc2 -

    float u  = fmaf(rb.x, tf, rb.z);                  // x-linear const
    float v  = fmaf(rb.y, tf, rb.w);                  // y-linear const
    float w0 = fmaf(fmaf(ra.z, tf, rc.x), tf, rc.y);  // const

    float Brow[4], Crow[4];
    float smin = 1e30f;
#pragma unroll
    for (int rr = 0; rr < 4; ++rr) {
        float yf = y0f + (float)rr;
        float B = fmaf(ra.w, yf, u);
        float C = fmaf(fmaf(ra.y, yf, v), yf, w0);
        Brow[rr] = B;
        Crow[rr] = C;
        smin = fminf(smin, fmaf(-B * B, rc.z, C));    // unclamped min over x
    }
    bool keep = smin < 16.0f;                         // e^-16 ~ 1.1e-7

    // ---- phase 2: deterministic compaction (gaussian-index order) ----
    unsigned long long mask = __ballot(keep);
    if (lane == 0) cnt_lds[wv] = (int)__popcll(mask);
    __syncthreads();

    int base = 0;
    for (int w = 0; w < wv; ++w) base += cnt_lds[w];
    int S = cnt_lds[0] + cnt_lds[1] + cnt_lds[2] + cnt_lds[3];
    S = __builtin_amdgcn_readfirstlane(S);

    if (keep) {
        int pos = __builtin_amdgcn_mbcnt_hi(
                      (unsigned)(mask >> 32),
                      __builtin_amdgcn_mbcnt_lo((unsigned)mask, 0));
        int slot = base + pos;
        float4* l4 = (float4*)recs;
        l4[slot * 3 + 0] = (float4){kneg * ra.x, rd.x, rd.y, rd.z};
        l4[slot * 3 + 1] = (float4){kneg * Brow[0], kneg * Crow[0],
                                    kneg * Brow[1], kneg * Crow[1]};
        l4[slot * 3 + 2] = (float4){kneg * Brow[2], kneg * Crow[2],
                                    kneg * Brow[3], kneg * Crow[3]};
    }
    __syncthreads();

    // ---- phase 3: blend S survivors, 2 px per thread ----
    const float x1 = (float)lane;
    const float x2 = x1 + 64.f;
    float a0 = 0.f, a1 = 0.f, a2 = 0.f;
    float b0 = 0.f, b1 = 0.f, b2 = 0.f;
    const float4* lds4 = (const float4*)recs;

#pragma unroll 2
    for (int m = 0; m < S; ++m) {
        float4 af = lds4[m * 3];                                // {A,f0,f1,f2}
        float2 bc = *(const float2*)&recs[m * 12 + 4 + 2 * wv]; // {B,C} my row
        float s1 = fmaf(fmaf(af.x, x1, bc.x), x1, bc.y);
        float s2 = fmaf(fmaf(af.x, x2, bc.x), x2, bc.y);
        float w1 = __builtin_amdgcn_exp2f(s1);
        float w2 = __builtin_amdgcn_exp2f(s2);
        a0 = fmaf(w1, af.y, a0);
        a1 = fmaf(w1, af.z, a1);
        a2 = fmaf(w1, af.w, a2);
        b0 = fmaf(w2, af.y, b0);
        b1 = fmaf(w2, af.z, b1);
        b2 = fmaf(w2, af.w, b2);
    }

    // layout: [3][H][W][T], base = (y*W + x)*T + t ; second pixel at x+64
    const int r = r0 + wv;
    const int y = r & 127, t = r >> 7;
    const int base_o = (y * WW + lane) * TT + t;
    float* d = dst + (size_t)blockIdx.y * P3;
    d[base_o] = a0;
    d[base_o + 64 * TT] = b0;
    d[base_o + PP] = a1;
    d[base_o + PP + 64 * TT] = b1;
    d[base_o + 2 * PP] = a2;
    d[base_o + 2 * PP + 64 * TT] = b2;
}

// ---------------------------------------------------------------------------
// Kernel C: sum SPLIT partials, clip, write out.
// ---------------------------------------------------------------------------
__global__ __launch_bounds__(256) void gv_reduce(
    const float* __restrict__ ws, float* __restrict__ out)
{
    const int i = blockIdx.x * 256 + threadIdx.x;
    const float4* w4 = (const float4*)ws;
    float4 a = w4[i];
#pragma unroll
    for (int s = 1; s < SPLIT; ++s) {
        float4 b = w4[(size_t)s * (P3 / 4) + i];
        a.x += b.x; a.y += b.y; a.z += b.z; a.w += b.w;
    }
    a.x = fminf(fmaxf(a.x, 0.f), 1.f);
    a.y = fminf(fmaxf(a.y, 0.f), 1.f);
    a.z = fminf(fmaxf(a.z, 0.f), 1.f);
    a.w = fminf(fmaxf(a.w, 0.f), 1.f);
    ((float4*)out)[i] = a;
}

// ---------------------------------------------------------------------------
// Dense fallback (no workspace): full setup in-block, clip, direct out.
// ---------------------------------------------------------------------------
__global__ __launch_bounds__(256) void gv_dense(
    const float* __restrict__ xyz,
    const float* __restrict__ chol,
    const float* __restrict__ feat,
    const float* __restrict__ opac,
    float* __restrict__ dst)
{
    __shared__ __align__(16) float lds[1024 * 12];

    const int tid = threadIdx.x;
    const int r0 = blockIdx.x * 4;
    const float kneg = -1.44269504088896340736f;

    for (int k = tid; k < 1024; k += 256) {
        const int n = k;
        float vx = xyz[n * 3 + 0], vy = xyz[n * 3 + 1], vt = xyz[n * 3 + 2];
        float mx = 0.5f * ((tanhf(vx) + 1.f) * (float)WW - 1.f);
        float my = 0.5f * ((tanhf(vy) + 1.f) * (float)HH - 1.f);
        float mt = 0.5f * ((tanhf(vt) + 1.f) * (float)TT - 1.f);
        float c0 = chol[n * 6 + 0] + 0.5f;
        float c1 = chol[n * 6 + 1];
        float c2 = chol[n * 6 + 2] + 0.5f;
        float c3 = chol[n * 6 + 3] + 0.5f;
        float c4 = chol[n * 6 + 4];
        float c5 = chol[n * 6 + 5] + 0.5f;
        float a  = c0 * c0, b = c0 * c1, cc = c0 * c2;
        float d  = c1 * c1 + c3 * c3;
        float e  = c1 * c2 + c3 * c4;
        float f  = c2 * c2 + c4 * c4 + c5 * c5;
        float A00 = d * f - e * e, A01 = cc * e - b * f, A02 = b * e - cc * d;
        float A11 = a * f - cc * cc, A12 = b * cc - a * e, A22 = a * d - b * b;
        float det = a * A00 + b * A01 + cc * A02;
        float rdet = 1.f / det;
        float Q00 = A00 * rdet, Q01 = A01 * rdet, Q02 = A02 * rdet;
        float Q11 = A11 * rdet, Q12 = A12 * rdet, Q22 = A22 * rdet;
        float qmx = Q00 * mx + Q01 * my + Q02 * mt;
        float qmy = Q01 * mx + Q11 * my + Q12 * mt;
        float qmt = Q02 * mx + Q12 * my + Q22 * mt;
        float cst = 0.5f * (mx * qmx + my * qmy + mt * qmt);
        float G0 = 0.5f * Q00, G1 = 0.5f * Q11, G2 = 0.5f * Q22;
        float G3 = Q01, G4 = Q02, G5 = Q12;
        float G6 = -qmx, G7 = -qmy, G8 = -qmt, G9 = cst;
        float op = opac[n];
        lds[k * 12 + 0] = kneg * G0;
        lds[k * 12 + 1] = op * feat[n * 3 + 0];
        lds[k * 12 + 2] = op * feat[n * 3 + 1];
        lds[k * 12 + 3] = op * feat[n * 3 + 2];
#pragma unroll
        for (int rr = 0; rr < 4; ++rr) {
            const int r = r0 + rr;
            const float yf = (float)(r & 127);
            const float tf = (float)(r >> 7);
            lds[k * 12 + 4 + 2 * rr] = kneg * (G3 * yf + G4 * tf + G6);
            lds[k * 12 + 5 + 2 * rr] = kneg * (G1 * yf * yf + G2 * tf * tf
                + G5 * yf * tf + G7 * yf + G8 * tf + G9);
        }
    }
    __syncthreads();

    const int wv = tid >> 6;
    const float x1 = (float)(tid & 63);
    const float x2 = x1 + 64.f;
    float a0 = 0.f, a1 = 0.f, a2 = 0.f;
    float b0 = 0.f, b1 = 0.f, b2 = 0.f;
    const float4* lds4 = (const float4*)lds;

#pragma unroll 8
    for (int k = 0; k < 1024; ++k) {
        float4 af = lds4[k * 3];
        float2 bc = *(const float2*)&lds[k * 12 + 4 + 2 * wv];
        float s1 = fmaf(fmaf(af.x, x1, bc.x), x1, bc.y);
        float s2 = fmaf(fmaf(af.x, x2, bc.x), x2, bc.y);
        float w1 = __builtin_amdgcn_exp2f(s1);
        float w2 = __builtin_amdgcn_exp2f(s2);
        a0 = fmaf(w1, af.y, a0); a1 = fmaf(w1, af.z, a1); a2 = fmaf(w1, af.w, a2);
        b0 = fmaf(w2, af.y, b0); b1 = fmaf(w2, af.z, b1); b2 = fmaf(w2, af.w, b2);
    }

    a0 = fminf(fmaxf(a0, 0.f), 1.f); a1 = fminf(fmaxf(a1, 0.f), 1.f);
    a2 = fminf(fmaxf(a2, 0.f), 1.f); b0 = fminf(fmaxf(b0, 0.f), 1.f);
    b1 = fminf(fmaxf(b1, 0.f), 1.f); b2 = fminf(fmaxf(b2, 0.f), 1.f);

    const int r = r0 + wv;
    const int y = r & 127, t = r >> 7;
    const int base = (y * WW + (tid & 63)) * TT + t;
    dst[base] = a0;
    dst[base + 64 * TT] = b0;
    dst[base + PP] = a1;
    dst[base + PP + 64 * TT] = b1;
    dst[base + 2 * PP] = a2;
    dst[base + 2 * PP + 64 * TT] = b2;
}

extern "C" void kernel_launch(void* const* d_in, const int* in_sizes, int n_in,
                              void* d_out, int out_size, void* d_ws, size_t ws_size,
                              hipStream_t stream) {
    const float* xyz  = (const float*)d_in[0];
    const float* chol = (const float*)d_in[1];
    const float* feat = (const float*)d_in[2];
    const float* opac = (const float*)d_in[3];
    float* out = (float*)d_out;
    float* ws  = (float*)d_ws;

    const int pixel_blocks = (TT * HH) / 4;          // 256 blocks of 4 rows
    const size_t need = (size_t)(RECTOT + SPLIT * P3) * sizeof(float);

    if (ws_size >= need) {
        float* recs_g = ws;                           // 64 KB records
        float* partials = ws + RECTOT;                // SPLIT x P3 partials
        gv_prep<<<(NG + 255) / 256, 256, 0, stream>>>(xyz, chol, feat, opac, recs_g);
        gv_cull<<<dim3(pixel_blocks, SPLIT), 256, 0, stream>>>(recs_g, partials);
        gv_reduce<<<P3 / 4 / 256, 256, 0, stream>>>(partials, out);
    } else {
        gv_dense<<<pixel_blocks, 256, 0, stream>>>(xyz, chol, feat, opac, out);
    }
}

// Round 7
// 14.364 us; speedup vs baseline: 3.0644x; 1.5104x over previous
//
#include <hip/hip_runtime.h>
#include <math.h>

#define HH 128
#define WW 128
#define TT 8
#define NG 1024
#define PP (HH * WW * TT)      // 131072 pixels

// tanh via exp2: tanh(x) = 1 - 2/(exp2(2*log2e*x)+1). ~1e-7 rel err, deterministic.
__device__ __forceinline__ float fast_tanh(float x) {
    float e = __builtin_amdgcn_exp2f(x * 2.885390081777926814f);
    return 1.f - 2.f * __builtin_amdgcn_rcpf(e + 1.f);
}

// ---------------------------------------------------------------------------
// Single fused kernel. Block = 256 threads = 4 waves; covers 2 rows
// (r = t*128 + y): waves {0,1} -> row 0 (x-halves 0/1), waves {2,3} -> row 1.
// One pixel per lane.
// Stage A: cheap conservative cull of all NG gaussians: min over continuous
//   (x,t) of sigma at fixed y is dy^2/(2*Sigma_yy); Sigma_yy = c1^2+c3^2 from
//   raw cholesky; keep iff dmin^2 < 32*Sigma_yy  (sigma < 16, e^-16 ~ 1e-7).
//   Deterministic index-ordered ballot compaction of survivor indices.
// Stage B: full setup (tanh means, L L^T, 3x3 inverse, per-row B,C) for the
//   ~S survivors only; records to LDS {A, f0, f1, f2, B0, C0, B1, C1}*(-log2e
//   on A,B,C).
// Stage C: blend S survivors per pixel: Horner + exp2 + 3 blends; clip; out.
// ---------------------------------------------------------------------------
__global__ __launch_bounds__(256) void gv_fused(
    const float* __restrict__ xyz,
    const float* __restrict__ chol,
    const float* __restrict__ feat,
    const float* __restrict__ opac,
    float* __restrict__ out)
{
    __shared__ __align__(16) float recs[NG * 8];   // 32 KB survivor records
    __shared__ int sidx[NG];                       // 4 KB survivor indices
    __shared__ int cnt_lds[4];

    const int tid = threadIdx.x;
    const int lane = tid & 63;
    const int wv = tid >> 6;
    const int r0 = blockIdx.x * 2;                 // rows r0, r0+1 (same t)
    const float y0f = (float)(r0 & 127);
    const float tf  = (float)(r0 >> 7);
    const float kneg = -1.44269504088896340736f;   // -log2(e)

    // ---- stage A: cheap y-band cull over all NG gaussians ----
    int S_run = 0;
    for (int it = 0; it < NG / 256; ++it) {
        const int n = it * 256 + tid;
        float vy = xyz[n * 3 + 1];
        float c1 = chol[n * 6 + 1];
        float c3 = chol[n * 6 + 3] + 0.5f;
        float my = fmaf(fast_tanh(vy), 64.f, 63.5f);   // 0.5*((tanh+1)*128-1)
        float syy = fmaf(c1, c1, c3 * c3);             // Sigma_yy
        float d0 = my - y0f;
        float d1 = d0 - 1.f;
        float dmin = fminf(fabsf(d0), fabsf(d1));
        bool keep = dmin * dmin < 32.f * syy;

        unsigned long long mask = __ballot(keep);
        if (lane == 0) cnt_lds[wv] = (int)__popcll(mask);
        __syncthreads();
        int base = S_run;
        for (int w = 0; w < wv; ++w) base += cnt_lds[w];
        int tot = cnt_lds[0] + cnt_lds[1] + cnt_lds[2] + cnt_lds[3];
        if (keep) {
            int pos = __builtin_amdgcn_mbcnt_hi(
                          (unsigned)(mask >> 32),
                          __builtin_amdgcn_mbcnt_lo((unsigned)mask, 0));
            sidx[base + pos] = n;
        }
        S_run += tot;
        __syncthreads();
    }
    const int S = S_run;                            // uniform across block

    // ---- stage B: full setup for survivors only ----
    for (int j = tid; j < S; j += 256) {
        const int n = sidx[j];
        float vx = xyz[n * 3 + 0], vy = xyz[n * 3 + 1], vt = xyz[n * 3 + 2];
        float mx = 0.5f * ((fast_tanh(vx) + 1.f) * (float)WW - 1.f);
        float my = 0.5f * ((fast_tanh(vy) + 1.f) * (float)HH - 1.f);
        float mt = 0.5f * ((fast_tanh(vt) + 1.f) * (float)TT - 1.f);

        float c0 = chol[n * 6 + 0] + 0.5f;
        float c1 = chol[n * 6 + 1];
        float c2 = chol[n * 6 + 2] + 0.5f;
        float c3 = chol[n * 6 + 3] + 0.5f;
        float c4 = chol[n * 6 + 4];
        float c5 = chol[n * 6 + 5] + 0.5f;

        // Sigma = L L^T
        float a  = c0 * c0;
        float b  = c0 * c1;
        float cc = c0 * c2;
        float d  = c1 * c1 + c3 * c3;
        float e  = c1 * c2 + c3 * c4;
        float f  = c2 * c2 + c4 * c4 + c5 * c5;

        // symmetric 3x3 inverse via adjugate
        float A00 = d * f - e * e;
        float A01 = cc * e - b * f;
        float A02 = b * e - cc * d;
        float A11 = a * f - cc * cc;
        float A12 = b * cc - a * e;
        float A22 = a * d - b * b;
        float det = a * A00 + b * A01 + cc * A02;
        float rdet = 1.f / det;
        float Q00 = A00 * rdet, Q01 = A01 * rdet, Q02 = A02 * rdet;
        float Q11 = A11 * rdet, Q12 = A12 * rdet, Q22 = A22 * rdet;

        float qmx = Q00 * mx + Q01 * my + Q02 * mt;
        float qmy = Q01 * mx + Q11 * my + Q12 * mt;
        float qmt = Q02 * mx + Q12 * my + Q22 * mt;
        float cst = 0.5f * (mx * qmx + my * qmy + mt * qmt);

        float G0 = 0.5f * Q00, G1 = 0.5f * Q11, G2 = 0.5f * Q22;
        float G3 = Q01, G4 = Q02, G5 = Q12;
        float G6 = -qmx, G7 = -qmy, G8 = -qmt, G9 = cst;

        // fold t (block-constant), then the block's two rows
        float u  = fmaf(G4, tf, G6);
        float v  = fmaf(G5, tf, G7);
        float w0 = fmaf(fmaf(G2, tf, G8), tf, G9);
        float B0 = fmaf(G3, y0f, u);
        float C0 = fmaf(fmaf(G1, y0f, v), y0f, w0);
        float y1f = y0f + 1.f;
        float B1 = fmaf(G3, y1f, u);
        float C1 = fmaf(fmaf(G1, y1f, v), y1f, w0);

        float op = opac[n];
        float4* l4 = (float4*)recs;
        l4[j * 2 + 0] = (float4){kneg * G0, op * feat[n * 3 + 0],
                                 op * feat[n * 3 + 1], op * feat[n * 3 + 2]};
        l4[j * 2 + 1] = (float4){kneg * B0, kneg * C0, kneg * B1, kneg * C1};
    }
    __syncthreads();

    // ---- stage C: blend S survivors, 1 px per lane ----
    const int rowi = wv >> 1;
    const int x = (wv & 1) * 64 + lane;
    const float xf = (float)x;
    float a0 = 0.f, a1 = 0.f, a2 = 0.f;
    const float4* lds4 = (const float4*)recs;

#pragma unroll 4
    for (int m = 0; m < S; ++m) {
        float4 af = lds4[m * 2];                                // {A,f0,f1,f2}
        float2 bc = *(const float2*)&recs[m * 8 + 4 + 2 * rowi]; // {B,C} my row
        float s = fmaf(fmaf(af.x, xf, bc.x), xf, bc.y);
        float w = __builtin_amdgcn_exp2f(s);
        a0 = fmaf(w, af.y, a0);
        a1 = fmaf(w, af.z, a1);
        a2 = fmaf(w, af.w, a2);
    }

    a0 = fminf(fmaxf(a0, 0.f), 1.f);
    a1 = fminf(fmaxf(a1, 0.f), 1.f);
    a2 = fminf(fmaxf(a2, 0.f), 1.f);

    // layout: [3][H][W][T], base = (y*W + x)*T + t
    const int r = r0 + rowi;
    const int y = r & 127, t = r >> 7;
    const int base_o = (y * WW + x) * TT + t;
    out[base_o] = a0;
    out[base_o + PP] = a1;
    out[base_o + 2 * PP] = a2;
}

extern "C" void kernel_launch(void* const* d_in, const int* in_sizes, int n_in,
                              void* d_out, int out_size, void* d_ws, size_t ws_size,
                              hipStream_t stream) {
    const float* xyz  = (const float*)d_in[0];
    const float* chol = (const float*)d_in[1];
    const float* feat = (const float*)d_in[2];
    const float* opac = (const float*)d_in[3];
    float* out = (float*)d_out;

    const int blocks = (TT * HH) / 2;        // 512 blocks, 2 rows each
    gv_fused<<<blocks, 256, 0, stream>>>(xyz, chol, feat, opac, out);
}